// Round 7
// baseline (10891.953 us; speedup 1.0000x reference)
//
#include <hip/hip_runtime.h>
#include <stdint.h>

#define DD 200
#define MM 128
#define JJ 256
#define BB 32
#define TPB 1024
#define MEMSTRIDE 201

// Soft barrier: LDS visibility + execution sync, but does NOT drain vmcnt —
// global (weight) loads stay in flight across phase boundaries. Safe because
// all cross-thread data in this kernel moves through LDS only. Executed only
// in block-uniform control flow (no barrier divergence).
#define SOFTBAR() asm volatile("s_waitcnt lgkmcnt(0)\n\ts_barrier" ::: "memory")

// clang-native 16B vector; component access via [] only (swizzle names are
// rejected in HIP C++ mode on this typedef).
typedef float f4 __attribute__((ext_vector_type(4)));

__device__ inline float sigm(float x) { return 1.f / (1.f + expf(-x)); }

// acc_i += w[i]*v[i]  (spread quad across 4 accumulators)
__device__ inline void fma4spread(float& a0, float& a1, float& a2, float& a3, f4 w, f4 v) {
  a0 = fmaf(w[0], v[0], a0); a1 = fmaf(w[1], v[1], a1);
  a2 = fmaf(w[2], v[2], a2); a3 = fmaf(w[3], v[3], a3);
}

// acc += dot(w, v)  (whole quad into one accumulator)
__device__ inline float dot4acc(float acc, f4 w, f4 v) {
  acc = fmaf(w[0], v[0], acc); acc = fmaf(w[1], v[1], acc);
  acc = fmaf(w[2], v[2], acc); acc = fmaf(w[3], v[3], acc);
  return acc;
}

// ---- weight prep: transpose to k-major, pack fp32 QUADS along k ----

__global__ void pack_gates_w(const float* __restrict__ w_ih, const float* __restrict__ w_hh,
                             const float* __restrict__ b_ih, const float* __restrict__ b_hh,
                             float* __restrict__ Wg4, float* __restrict__ bg) {
  int idx = blockIdx.x * blockDim.x + threadIdx.x;
  if (idx < 100 * 800) {
    int k4 = idx / 800, g = idx - k4 * 800;
    #pragma unroll
    for (int e = 0; e < 4; ++e) {
      int k = 4 * k4 + e;
      Wg4[4 * idx + e] = (k < DD) ? w_ih[g * DD + k] : w_hh[g * DD + (k - DD)];
    }
  }
  if (idx < 800) bg[idx] = b_ih[idx] + b_hh[idx];
}

__global__ void pack_fc1(const float* __restrict__ w_fc1, float* __restrict__ Tfc14) {
  int idx = blockIdx.x * blockDim.x + threadIdx.x;
  if (idx < 100 * DD) {
    int k4 = idx / DD, d = idx - k4 * DD;
    const float* p = w_fc1 + d * 400 + 4 * k4;
    #pragma unroll
    for (int e = 0; e < 4; ++e) Tfc14[4 * idx + e] = p[e];
  }
}

__global__ void pack_fc(const float* __restrict__ w_fc, float* __restrict__ Tfc4) {
  int idx = blockIdx.x * blockDim.x + threadIdx.x;
  if (idx < 50 * DD) {
    int k4 = idx / DD, d = idx - k4 * DD;
    const float* p = w_fc + d * DD + 4 * k4;
    #pragma unroll
    for (int e = 0; e < 4; ++e) Tfc4[4 * idx + e] = p[e];
  }
}

// ---- main: one block per (b, parity) chain; mem resident in LDS ----
__global__ __launch_bounds__(TPB, 4)
void chain_kernel(const float* __restrict__ cosb, const float* __restrict__ bank,
                  const float* __restrict__ mem_a, const float* __restrict__ mem_b,
                  const float* __restrict__ b_fc, const float* __restrict__ b_fc1,
                  const f4* __restrict__ Wg4, const f4* __restrict__ Tfc14,
                  const f4* __restrict__ Tfc4, const float* __restrict__ bg,
                  float* __restrict__ out)
{
  extern __shared__ float mem_s[];               // [128][201] = 102,912 B
  __shared__ __align__(16) float qh_s[400];      // [0:200)=q, [200:400)=h
  __shared__ __align__(16) float xq_s[400];      // [200:400)=q_old (concat tail)
  __shared__ __align__(16) float qsv_s[DD];
  __shared__ __align__(16) float bank_sh[2][DD];
  __shared__ __align__(16) float q0_s[2][DD];
  __shared__ __align__(16) float cos_s[2][MM];
  __shared__ __align__(16) float gates_s[800];
  __shared__ __align__(16) float logp_s[1024];
  __shared__ __align__(16) float hp_s[400];
  __shared__ __align__(16) float xp_s[400];
  __shared__ __align__(16) float fq_s[400];
  __shared__ __align__(16) float att_s[MM];

  const int t = threadIdx.x;
  const int par = blockIdx.x & 1;
  const int b = blockIdx.x >> 1;

  const f4* wpC = Wg4 + t;                       // valid for t<800
  const int khH = (t >= DD) ? 1 : 0;
  const int dH = t - khH * DD;                   // valid for t<400
  const f4* wpH2 = Tfc14 + dH + khH * 50 * DD;
  const f4* wpK2 = Tfc4 + dH + khH * 25 * DD;

  // prologue: load mem + stage step-0 cos/bank
  const float* msrc = (par ? mem_b : mem_a) + b * MM * DD;
  for (int i = t; i < MM * DD; i += TPB) {
    int m = i / DD, d = i - m * DD;
    mem_s[m * MEMSTRIDE + d] = msrc[i];
  }
  if (t < MM) cos_s[0][t] = cosb[(b * JJ + par) * MM + t];
  else if (t < MM + DD) bank_sh[0][t - MM] = bank[(par * BB + b) * DD + (t - MM)];
  __syncthreads();

  // q0 for step 0 (prologue only)
  if (t < DD) {
    float a0 = b_fc[t], a1 = 0.f, a2 = 0.f, a3 = 0.f;
    const f4* bv = reinterpret_cast<const f4*>(bank_sh[0]);
    const f4* wp = Tfc4 + t;
    #pragma unroll 5
    for (int k4 = 0; k4 < 50; ++k4) {
      fma4spread(a0, a1, a2, a3, wp[k4 * DD], bv[k4]);
    }
    q0_s[0][t] = (a0 + a1) + (a2 + a3);
  }
  __syncthreads();

  float c_reg = 0.f, sv_reg = 0.f;

  for (int s = 0; s < JJ / 2; ++s) {
    const int j = 2 * s + par;
    const int cur = s & 1, nxt = cur ^ 1;
    // prefetch registers (zero-init; assigned/consumed under matching predicates)
    f4 cp0 = {0,0,0,0}, cp1 = {0,0,0,0}, cp2 = {0,0,0,0}, cp3 = {0,0,0,0};
    f4 cp4 = {0,0,0,0}, cp5 = {0,0,0,0}, cp6 = {0,0,0,0}, cp7 = {0,0,0,0};
    f4 kp0 = {0,0,0,0}, kp1 = {0,0,0,0}, kp2 = {0,0,0,0}, kp3 = {0,0,0,0};

    // Phase A: h0 partials (2-way m-split) | stage next cos/bank
    if (t < 400) {
      int half = (t >= DD) ? 1 : 0;
      int d = t - half * DD;
      const float* cs = cos_s[cur] + half * 64;
      const float* mp = mem_s + (half * 64) * MEMSTRIDE + d;
      float a0 = 0.f, a1 = 0.f;
      #pragma unroll 4
      for (int m = 0; m < 64; m += 2) {
        a0 = fmaf(cs[m], mp[m * MEMSTRIDE], a0);
        a1 = fmaf(cs[m + 1], mp[(m + 1) * MEMSTRIDE], a1);
      }
      hp_s[half * DD + d] = a0 + a1;
    } else if (t < 400 + MM + DD) {
      if (s + 1 < JJ / 2) {
        int u = t - 400, j2 = j + 2;
        if (u < MM) cos_s[nxt][u] = cosb[(b * JJ + j2) * MM + u];
        else bank_sh[nxt][u - MM] = bank[(j2 * BB + b) * DD + (u - MM)];
      }
    }
    SOFTBAR();

    // Phase B: reduce h partials, install q0 | pre-issue C(p=0) weight loads
    if (t < DD) {
      float h = hp_s[t] + hp_s[DD + t];
      float q = q0_s[cur][t];
      qh_s[200 + t] = h;
      qh_s[t] = q;
      xq_s[200 + t] = q;
      c_reg = 0.f;
    }
    if (t < 800) {
      cp0 = wpC[0];        cp1 = wpC[800];      cp2 = wpC[2 * 800]; cp3 = wpC[3 * 800];
      cp4 = wpC[4 * 800];  cp5 = wpC[5 * 800];  cp6 = wpC[6 * 800]; cp7 = wpC[7 * 800];
    }
    SOFTBAR();

    for (int p = 0; p < 3; ++p) {
      // Phase C: gates GEMV (t<800, k4 0..7 from prefetch) | next-step q0 (p==0, waves 13+)
      if (t < 800) {
        const f4* qv4 = reinterpret_cast<const f4*>(qh_s);
        float a0 = bg[t], a1 = 0.f, a2 = 0.f, a3 = 0.f;
        a0 = dot4acc(a0, cp0, qv4[0]);
        a1 = dot4acc(a1, cp1, qv4[1]);
        a2 = dot4acc(a2, cp2, qv4[2]);
        a3 = dot4acc(a3, cp3, qv4[3]);
        a0 = dot4acc(a0, cp4, qv4[4]);
        a1 = dot4acc(a1, cp5, qv4[5]);
        a2 = dot4acc(a2, cp6, qv4[6]);
        a3 = dot4acc(a3, cp7, qv4[7]);
        for (int k4 = 8; k4 < 100; k4 += 4) {
          f4 w0 = wpC[k4 * 800], w1 = wpC[(k4 + 1) * 800];
          f4 w2 = wpC[(k4 + 2) * 800], w3 = wpC[(k4 + 3) * 800];
          a0 = dot4acc(a0, w0, qv4[k4]);
          a1 = dot4acc(a1, w1, qv4[k4 + 1]);
          a2 = dot4acc(a2, w2, qv4[k4 + 2]);
          a3 = dot4acc(a3, w3, qv4[k4 + 3]);
        }
        gates_s[t] = (a0 + a1) + (a2 + a3);
      } else if (p == 0 && t >= 832 && s + 1 < JJ / 2) {
        int u = t - 832;
        for (int d = u; d < DD; d += 192) {
          float a0 = b_fc[d], a1 = 0.f, a2 = 0.f, a3 = 0.f;
          const f4* bv = reinterpret_cast<const f4*>(bank_sh[nxt]);
          const f4* wp = Tfc4 + d;
          #pragma unroll 5
          for (int k4 = 0; k4 < 50; ++k4) {
            fma4spread(a0, a1, a2, a3, wp[k4 * DD], bv[k4]);
          }
          q0_s[nxt][d] = (a0 + a1) + (a2 + a3);
        }
      }
      SOFTBAR();

      // Phase D: LSTM cell
      if (t < DD) {
        float ig = gates_s[t], fg = gates_s[200 + t], gg = gates_s[400 + t], og = gates_s[600 + t];
        c_reg = sigm(fg) * c_reg + sigm(ig) * tanhf(gg);
        float h = sigm(og) * tanhf(c_reg);
        qh_s[200 + t] = h;
        xq_s[200 + t] = qh_s[t];   // stash current q for the concat
      }
      SOFTBAR();

      // Phase E: pre-issue fc1 weight loads (t<400), then logits partials (all)
      f4 hq0 = {0,0,0,0}, hq1 = {0,0,0,0}, hq2 = {0,0,0,0}, hq3 = {0,0,0,0};
      if (t < 400) {
        hq0 = wpH2[0]; hq1 = wpH2[DD]; hq2 = wpH2[2 * DD]; hq3 = wpH2[3 * DD];
      }
      {
        int qd = t >> 7, m = t & 127;
        const float* hv = qh_s + 200 + qd * 25;
        const float* mrow = mem_s + m * MEMSTRIDE + qd * 25;
        float l0 = 0.f, l1 = 0.f;
        #pragma unroll
        for (int d = 0; d < 24; d += 2) {
          l0 = fmaf(hv[d], mrow[d], l0);
          l1 = fmaf(hv[d + 1], mrow[d + 1], l1);
        }
        l0 = fmaf(hv[24], mrow[24], l0);
        logp_s[qd * 128 + m] = l0 + l1;
      }
      SOFTBAR();

      // Phase F: softmax over 128, wave 0
      if (t < 64) {
        float l0 = 0.f, l1 = 0.f;
        #pragma unroll
        for (int qd = 0; qd < 8; ++qd) {
          l0 += logp_s[qd * 128 + t];
          l1 += logp_s[qd * 128 + t + 64];
        }
        float mx = fmaxf(l0, l1);
        #pragma unroll
        for (int o = 1; o < 64; o <<= 1) mx = fmaxf(mx, __shfl_xor(mx, o));
        float e0 = expf(l0 - mx), e1 = expf(l1 - mx);
        float ssum = e0 + e1;
        #pragma unroll
        for (int o = 1; o < 64; o <<= 1) ssum += __shfl_xor(ssum, o);
        float inv = 1.f / ssum;
        att_s[t] = e0 * inv;
        att_s[t + 64] = e1 * inv;
      }
      SOFTBAR();

      // Phase G: x partials (2-way m-split)
      if (t < 400) {
        int half = (t >= DD) ? 1 : 0;
        int d = t - half * DD;
        const float* as = att_s + half * 64;
        const float* mp = mem_s + (half * 64) * MEMSTRIDE + d;
        float a0 = 0.f, a1 = 0.f;
        #pragma unroll 4
        for (int m = 0; m < 64; m += 2) {
          a0 = fmaf(as[m], mp[m * MEMSTRIDE], a0);
          a1 = fmaf(as[m + 1], mp[(m + 1) * MEMSTRIDE], a1);
        }
        xp_s[half * DD + d] = a0 + a1;
      }
      SOFTBAR();

      // Phase H: fc1 partials (2-way k-split), k4 0..3 from prefetch
      if (t < 400) {
        float a0 = 0.f, a1 = 0.f, a2 = 0.f, a3 = 0.f;
        if (khH == 0) {
          const f4* x0 = reinterpret_cast<const f4*>(xp_s);
          const f4* x1 = reinterpret_cast<const f4*>(xp_s + DD);
          fma4spread(a0, a1, a2, a3, hq0, x0[0] + x1[0]);
          fma4spread(a0, a1, a2, a3, hq1, x0[1] + x1[1]);
          fma4spread(a0, a1, a2, a3, hq2, x0[2] + x1[2]);
          fma4spread(a0, a1, a2, a3, hq3, x0[3] + x1[3]);
          #pragma unroll 2
          for (int k4 = 4; k4 < 50; ++k4) {
            fma4spread(a0, a1, a2, a3, wpH2[k4 * DD], x0[k4] + x1[k4]);
          }
        } else {
          const f4* qv = reinterpret_cast<const f4*>(xq_s);
          fma4spread(a0, a1, a2, a3, hq0, qv[50]);
          fma4spread(a0, a1, a2, a3, hq1, qv[51]);
          fma4spread(a0, a1, a2, a3, hq2, qv[52]);
          fma4spread(a0, a1, a2, a3, hq3, qv[53]);
          #pragma unroll 2
          for (int kk = 4; kk < 50; ++kk) {
            fma4spread(a0, a1, a2, a3, wpH2[kk * DD], qv[50 + kk]);
          }
        }
        fq_s[khH * DD + dH] = (a0 + a1) + (a2 + a3);
      }
      SOFTBAR();

      // Phase I: reduce fc1, emit on last p | pre-issue next C or K weight loads
      if (t < DD) {
        float qn = fq_s[t] + fq_s[DD + t] + b_fc1[t];
        qh_s[t] = qn;
        if (p == 2) {
          out[(b * JJ + j) * DD + t] = qn;
          sv_reg = mem_s[s * MEMSTRIDE + t];
          qsv_s[t] = qn + sv_reg;
        }
      }
      if (p < 2) {
        if (t < 800) {
          cp0 = wpC[0];        cp1 = wpC[800];      cp2 = wpC[2 * 800]; cp3 = wpC[3 * 800];
          cp4 = wpC[4 * 800];  cp5 = wpC[5 * 800];  cp6 = wpC[6 * 800]; cp7 = wpC[7 * 800];
        }
      } else if (t < 400) {
        kp0 = wpK2[0]; kp1 = wpK2[DD]; kp2 = wpK2[2 * DD]; kp3 = wpK2[3 * DD];
      }
      SOFTBAR();
    }

    // Phase K: final fc partials (2-way k-split), k4 0..3 from prefetch
    if (t < 400) {
      const f4* qv = reinterpret_cast<const f4*>(qsv_s);
      float a0 = 0.f, a1 = 0.f, a2 = 0.f, a3 = 0.f;
      fma4spread(a0, a1, a2, a3, kp0, qv[khH * 25]);
      fma4spread(a0, a1, a2, a3, kp1, qv[khH * 25 + 1]);
      fma4spread(a0, a1, a2, a3, kp2, qv[khH * 25 + 2]);
      fma4spread(a0, a1, a2, a3, kp3, qv[khH * 25 + 3]);
      #pragma unroll 3
      for (int kk = 4; kk < 25; ++kk) {
        fma4spread(a0, a1, a2, a3, wpK2[kk * DD], qv[khH * 25 + kk]);
      }
      fq_s[khH * DD + dH] = (a0 + a1) + (a2 + a3);
    }
    SOFTBAR();

    // Phase L: z, mem row update
    if (t < DD) {
      float z = tanhf(fq_s[t] + fq_s[DD + t] + 2.f * b_fc[t]);
      mem_s[s * MEMSTRIDE + t] = z * sv_reg;
    }
    SOFTBAR();
  }
}

extern "C" void kernel_launch(void* const* d_in, const int* in_sizes, int n_in,
                              void* d_out, int out_size, void* d_ws, size_t ws_size,
                              hipStream_t stream) {
  const float* cosb  = (const float*)d_in[0];
  const float* bank  = (const float*)d_in[1];
  const float* mem_a = (const float*)d_in[2];
  const float* mem_b = (const float*)d_in[3];
  const float* w_fc  = (const float*)d_in[4];
  const float* b_fc  = (const float*)d_in[5];
  const float* w_fc1 = (const float*)d_in[6];
  const float* b_fc1 = (const float*)d_in[7];
  const float* w_ih  = (const float*)d_in[8];
  const float* w_hh  = (const float*)d_in[9];
  const float* b_ih  = (const float*)d_in[10];
  const float* b_hh  = (const float*)d_in[11];

  char* ws = (char*)d_ws;
  float* Wg4   = (float*)(ws);              // 100*800*16 = 1,280,000 B
  float* Tfc14 = (float*)(ws + 1280000);    // 100*200*16 =   320,000 B
  float* Tfc4  = (float*)(ws + 1600000);    //  50*200*16 =   160,000 B
  float* bg    = (float*)(ws + 1760000);    // 800*4      =     3,200 B

  pack_gates_w<<<(100 * 800 + 255) / 256, 256, 0, stream>>>(w_ih, w_hh, b_ih, b_hh, Wg4, bg);
  pack_fc1<<<(100 * DD + 255) / 256, 256, 0, stream>>>(w_fc1, Tfc14);
  pack_fc<<<(50 * DD + 255) / 256, 256, 0, stream>>>(w_fc, Tfc4);

  int dynbytes = MM * MEMSTRIDE * sizeof(float);  // 102,912 B
  (void)hipFuncSetAttribute(reinterpret_cast<const void*>(chain_kernel),
                            hipFuncAttributeMaxDynamicSharedMemorySize, dynbytes);
  chain_kernel<<<64, TPB, dynbytes, stream>>>(cosb, bank, mem_a, mem_b, b_fc, b_fc1,
                                              (const f4*)Wg4, (const f4*)Tfc14,
                                              (const f4*)Tfc4, bg, (float*)d_out);
}